// Round 5
// baseline (627.215 us; speedup 1.0000x reference)
//
#include <hip/hip_runtime.h>
#include <hip/hip_bf16.h>
#include <stdint.h>

#define NND 3072
#define DD 300
#define HH 4
#define F2 1200
#define TNC 40   // ccgemm LDS pad (32 + 8)
#define BKF 64   // fattgemm K-step
#define TNF 72   // fattgemm LDS pad (64 + 8)

typedef __attribute__((ext_vector_type(8))) short short8v;
typedef __attribute__((ext_vector_type(4))) float f32x4;
typedef __hip_bfloat16 bf16;

__device__ inline float ldin(const void* p, size_t i, int isf32) {
    return isf32 ? ((const float*)p)[i]
                 : __bfloat162float(((const bf16*)p)[i]);
}

__device__ inline ushort f2bf(float x) {
    bf16 t = __float2bfloat16(x);
    return *reinterpret_cast<ushort*>(&t);
}

// ---- dtype sniffer: flags[0]=1 iff float inputs are f32; flags[1]=1 iff adj is int32
__global__ void k_detect(const void* emb, const void* adj, int* flags) {
    if (threadIdx.x == 0 && blockIdx.x == 0) {
        const uint16_t* u = (const uint16_t*)emb;
        int plaus = 0;
        for (int i = 0; i < 128; i++) {
            int e = (u[i] >> 7) & 0xFF;
            if (e >= 112 && e <= 143) plaus++;
        }
        flags[0] = (plaus < 100) ? 1 : 0;
        const uint8_t* b = (const uint8_t*)adj;
        int nz = 0;
        for (int i = 0; i < 256; i++) if ((i & 3) != 0 && b[i]) nz++;
        flags[1] = (nz == 0) ? 1 : 0;
    }
}

// ---- T[c][r] = A[r][c], output bf16.  grid = ((C+31)/32, (R+31)/32)
__global__ void k_transpose(const void* A, size_t baseOff, bf16* T, int R, int C,
                            const int* flags, int useFlag) {
    __shared__ bf16 t[32][33];
    int isf = useFlag ? flags[0] : 0;
    int rt = blockIdx.y * 32, ct = blockIdx.x * 32;
    int tx = threadIdx.x, ty = threadIdx.y;
    for (int i = 0; i < 4; i++) {
        int r = rt + ty + 8 * i, c = ct + tx;
        if (r < R && c < C)
            t[ty + 8 * i][tx] = __float2bfloat16(ldin(A, baseOff + (size_t)r * C + c, isf));
    }
    __syncthreads();
    for (int i = 0; i < 4; i++) {
        int c = ct + ty + 8 * i, r = rt + tx;
        if (c < C && r < R) T[(size_t)c * R + r] = t[tx][ty + 8 * i];
    }
}

// ---- u1 = W @ a[:C], u2 = W @ a[C:2C]
__global__ void k_uvec(const void* W, const void* a, float* u1, float* u2, int R, int C,
                       long Wb, long ab, long ub, const int* flags) {
    int isf = flags[0];
    int h = blockIdx.y;
    int wid = threadIdx.x >> 6, lane = threadIdx.x & 63;
    int r = blockIdx.x * 4 + wid;
    if (r >= R) return;
    float s1 = 0.f, s2 = 0.f;
    for (int c = lane; c < C; c += 64) {
        float w = ldin(W, (size_t)h * Wb + (size_t)r * C + c, isf);
        s1 += w * ldin(a, (size_t)h * ab + c, isf);
        s2 += w * ldin(a, (size_t)h * ab + C + c, isf);
    }
    for (int o = 32; o; o >>= 1) { s1 += __shfl_down(s1, o); s2 += __shfl_down(s2, o); }
    if (lane == 0) { u1[(size_t)h * ub + r] = s1; u2[(size_t)h * ub + r] = s2; }
}

// ---- o1[i] = X[i,:]·u1, o2[i] = X[i,:]·u2
__global__ void k_gemv2(const void* X, const float* u1, const float* u2, float* o1, float* o2,
                        int M, int K, long ub, long ob, const int* flags, int useFlag) {
    int isf = useFlag ? flags[0] : 0;
    int h = blockIdx.y;
    const float* U1 = u1 + (size_t)h * ub;
    const float* U2 = u2 + (size_t)h * ub;
    int wid = threadIdx.x >> 6, lane = threadIdx.x & 63;
    int row = blockIdx.x * 4 + wid;
    if (row >= M) return;
    float s1 = 0.f, s2 = 0.f;
    for (int k = lane; k < K; k += 64) {
        float x = ldin(X, (size_t)row * K + k, isf);
        s1 += x * U1[k]; s2 += x * U2[k];
    }
    for (int o = 32; o; o >>= 1) { s1 += __shfl_down(s1, o); s2 += __shfl_down(s2, o); }
    if (lane == 0) { o1[(size_t)h * ob + row] = s1; o2[(size_t)h * ob + row] = s2; }
}

// ---- single-pass two-sided masked softmax denominators (no max shift: |e| is O(10))
__global__ __launch_bounds__(256) void k_stats(const float* __restrict__ Wh1A,
                                               const float* __restrict__ Wh2A, long hs,
                                               const void* __restrict__ adj, const int* __restrict__ flags,
                                               float* __restrict__ rspA, float* __restrict__ rsnA) {
    int h = blockIdx.y;
    const float* Wh1 = Wh1A + (size_t)h * hs;
    const float* Wh2 = Wh2A + (size_t)h * hs;
    int i = blockIdx.x;
    int tidx = threadIdx.x, wid = tidx >> 6, lane = tidx & 63;
    int adjInt = flags[1];
    const uint8_t* a8 = (const uint8_t*)adj;
    const int* a32 = (const int*)adj;
    float w1 = Wh1[i];
    float sp = 0.f, sn = 0.f;
    for (int j = tidx; j < NND; j += 256) {
        size_t idx = (size_t)i * NND + j;
        int on = adjInt ? a32[idx] : (int)a8[idx];
        if (on) {
            float z = w1 + Wh2[j];
            float e = fmaxf(z, 0.3f * z);
            sp += __expf(e);
            sn += __expf(-e);
        }
    }
    __shared__ float r1[4], r2[4];
    for (int o = 32; o; o >>= 1) { sp += __shfl_down(sp, o); sn += __shfl_down(sn, o); }
    if (lane == 0) { r1[wid] = sp; r2[wid] = sn; }
    __syncthreads();
    if (tidx == 0) {
        sp = r1[0] + r1[1] + r1[2] + r1[3];
        sn = r2[0] + r2[1] + r2[2] + r2[3];
        size_t o = (size_t)h * NND + i;
        rspA[o] = 1.0f / sp;
        rsnA[o] = -1.0f / sn;   // fold neg_att's minus sign
    }
}

// ---- fused attention GEMM, M-tile 32, N-tile 160, BK 64.
// CC[:,0:F] = diag(rsp)·(Ppos@Xt^T), CC[:,F:2F] = diag(rsn)·(Pneg@Xt^T)
// P = exp(±leaky(Wh1[i]+Wh2[j])) masked, built on the fly (no max shift).
// Xt: [nPad][3072] bf16, nPad >= gridDim.x*160. blockIdx.z = head.
__global__ __launch_bounds__(256) void k_fattgemm(
    const float* __restrict__ Wh1A, const float* __restrict__ Wh2A,
    const float* __restrict__ rspA, const float* __restrict__ rsnA, long hs,
    const void* __restrict__ adj, const int* __restrict__ flags,
    const bf16* __restrict__ Xt, bf16* __restrict__ CC,
    long ccHeadStride, int ccStride, int F) {
    __shared__ __align__(16) bf16 Ap[32 * TNF];
    __shared__ __align__(16) bf16 An[32 * TNF];
    int h = blockIdx.z;
    const float* Wh1 = Wh1A + (size_t)h * hs;
    const float* Wh2 = Wh2A + (size_t)h * hs;
    const float* rsp = rspA + (size_t)h * hs;
    const float* rsn = rsnA + (size_t)h * hs;
    bf16* C = CC + (size_t)h * ccHeadStride;
    int m0 = blockIdx.y * 32, n0 = blockIdx.x * 160;
    int tid = threadIdx.x, lane = tid & 63, w = tid >> 6, wr = w >> 1, wn = w & 1;
    int sm = tid >> 3;            // 0..31 row within tile
    int sk = (tid & 7) * 8;       // 0..56 k-offset (8 elements per thread)
    int srow = m0 + sm;
    float w1 = Wh1[srow];
    int adjInt = flags[1];
    const uint8_t* arow8 = (const uint8_t*)adj + (size_t)srow * NND;
    const int* arow32 = (const int*)adj + (size_t)srow * NND;
    f32x4 cp[5] = {};
    f32x4 cn[5] = {};
    int ar = wr * 16 + (lane & 15);
    int ko = (lane >> 4) * 8;
    const bf16* Bbase = Xt + (size_t)(n0 + wn * 80 + (lane & 15)) * NND + ko;

    for (int k0 = 0; k0 < NND; k0 += BKF) {
        unsigned msk = 0;
        if (!adjInt) {
            uint2 ab = *(const uint2*)(arow8 + k0 + sk);
            #pragma unroll
            for (int jj = 0; jj < 4; jj++) {
                if ((ab.x >> (8 * jj)) & 0xffu) msk |= 1u << jj;
                if ((ab.y >> (8 * jj)) & 0xffu) msk |= 1u << (4 + jj);
            }
        } else {
            int4 u = *(const int4*)(arow32 + k0 + sk);
            int4 v = *(const int4*)(arow32 + k0 + sk + 4);
            if (u.x) msk |= 1;  if (u.y) msk |= 2;   if (u.z) msk |= 4;   if (u.w) msk |= 8;
            if (v.x) msk |= 16; if (v.y) msk |= 32;  if (v.z) msk |= 64;  if (v.w) msk |= 128;
        }
        float4 wa = *(const float4*)(Wh2 + k0 + sk);
        float4 wb = *(const float4*)(Wh2 + k0 + sk + 4);
        float zs[8] = {wa.x, wa.y, wa.z, wa.w, wb.x, wb.y, wb.z, wb.w};
        ushort pu[8], qu[8];
        #pragma unroll
        for (int jj = 0; jj < 8; jj++) {
            float z = w1 + zs[jj];
            float e = fmaxf(z, 0.3f * z);            // leaky_relu(0.3)
            bool on = (msk >> jj) & 1u;
            float pe = on ? __expf(e) : 0.0f;
            float qe = on ? __expf(-e) : 0.0f;
            pu[jj] = f2bf(pe);
            qu[jj] = f2bf(qe);
        }
        __syncthreads();
        *(short8v*)&Ap[sm * TNF + sk] = *(const short8v*)pu;
        *(short8v*)&An[sm * TNF + sk] = *(const short8v*)qu;
        __syncthreads();
        #pragma unroll
        for (int kk = 0; kk < BKF; kk += 32) {
            short8v a  = *(const short8v*)&Ap[ar * TNF + kk + ko];
            short8v e8 = *(const short8v*)&An[ar * TNF + kk + ko];
            #pragma unroll
            for (int f = 0; f < 5; f++) {
                short8v b = *(const short8v*)(Bbase + (size_t)f * 16 * NND + k0 + kk);
                cp[f] = __builtin_amdgcn_mfma_f32_16x16x32_bf16(a,  b, cp[f], 0, 0, 0);
                cn[f] = __builtin_amdgcn_mfma_f32_16x16x32_bf16(e8, b, cn[f], 0, 0, 0);
            }
        }
    }
    int rbase = m0 + wr * 16 + (lane >> 4) * 4;
    #pragma unroll
    for (int r = 0; r < 4; r++) {
        int row = rbase + r;
        float sp_ = rsp[row], sn_ = rsn[row];
        #pragma unroll
        for (int f = 0; f < 5; f++) {
            int col = n0 + wn * 80 + f * 16 + (lane & 15);
            if (col < F) {
                C[(size_t)row * ccStride + col]     = __float2bfloat16(cp[f][r] * sp_);
                C[(size_t)row * ccStride + F + col] = __float2bfloat16(cn[f][r] * sn_);
            }
        }
    }
}

// ---- Out[:,off:off+N] = epi(A @ Bt^T); M-tile 32, N-tile 64; head-batched via blockIdx.z
__global__ __launch_bounds__(256) void k_ccgemm(const bf16* __restrict__ A0, const bf16* __restrict__ Bt0,
                                                bf16* __restrict__ Out, int K, int Ncols,
                                                int outStride, int outColOff0, int mode,
                                                long aHeadStride, long btHeadStride, int outColStep) {
    __shared__ __align__(16) bf16 Alds[32 * TNC];
    __shared__ __align__(16) bf16 Blds[64 * TNC];
    int h = blockIdx.z;
    const bf16* A = A0 + (size_t)h * aHeadStride;
    const bf16* Bt = Bt0 + (size_t)h * btHeadStride;
    int outColOff = outColOff0 + h * outColStep;
    int tid = threadIdx.x, lane = tid & 63, w = tid >> 6, wr = w >> 1, wc = w & 1;
    int m0 = blockIdx.y * 32, n0 = blockIdx.x * 64;
    int smA = tid >> 3, skA = (tid & 7) * 4;   // 32 rows × 4 el (8B)
    int smB = tid >> 2, skB = (tid & 3) * 8;   // 64 rows × 8 el (16B)
    f32x4 acc[2] = {};
    for (int k0 = 0; k0 < K; k0 += 32) {
        uint2 va = make_uint2(0, 0);
        uint4 vx = make_uint4(0, 0, 0, 0);
        if (k0 + skA < K) va = *(const uint2*)(A + (size_t)(m0 + smA) * K + k0 + skA);
        if (n0 + smB < Ncols && k0 + skB < K) vx = *(const uint4*)(Bt + (size_t)(n0 + smB) * K + k0 + skB);
        __syncthreads();
        *(uint2*)&Alds[smA * TNC + skA] = va;
        *(uint4*)&Blds[smB * TNC + skB] = vx;
        __syncthreads();
        int arr = wr * 16 + (lane & 15), koff = (lane >> 4) * 8;
        int br = wc * 32 + (lane & 15);
        short8v a0 = *(const short8v*)&Alds[arr * TNC + koff];
        short8v b0 = *(const short8v*)&Blds[br * TNC + koff];
        short8v b1 = *(const short8v*)&Blds[(br + 16) * TNC + koff];
        acc[0] = __builtin_amdgcn_mfma_f32_16x16x32_bf16(a0, b0, acc[0], 0, 0, 0);
        acc[1] = __builtin_amdgcn_mfma_f32_16x16x32_bf16(a0, b1, acc[1], 0, 0, 0);
    }
    for (int ni = 0; ni < 2; ni++) {
        int col = n0 + wc * 32 + ni * 16 + (lane & 15);
        if (col >= Ncols) continue;
        int rbase = m0 + wr * 16 + (lane >> 4) * 4;
        for (int r = 0; r < 4; r++) {
            float v = acc[ni][r];
            if (mode == 0) v = v > 0.f ? v : (__expf(v) - 1.0f);
            else           v = 1.0f / (1.0f + __expf(-v));
            Out[(size_t)(rbase + r) * outStride + outColOff + col] = __float2bfloat16(v);
        }
    }
}

__global__ void k_gather(const bf16* full, const int* ids, void* out, const int* flags) {
    int idx = blockIdx.x * 256 + threadIdx.x;
    if (idx >= 64 * DD) return;
    int t = idx / DD, d = idx - t * DD;
    float v = __bfloat162float(full[(size_t)ids[t] * DD + d]);
    if (flags[0]) ((float*)out)[idx] = v;
    else ((bf16*)out)[idx] = __float2bfloat16(v);
}

extern "C" void kernel_launch(void* const* d_in, const int* in_sizes, int n_in,
                              void* d_out, int out_size, void* d_ws, size_t ws_size,
                              hipStream_t stream) {
    const void* emb = d_in[0];
    const void* Whd = d_in[1];
    const void* ahd = d_in[2];
    const void* wth = d_in[3];
    const void* Wo  = d_in[4];
    const void* ao  = d_in[5];
    const void* wto = d_in[6];
    const void* adj = d_in[7];
    const int* tid  = (const int*)d_in[8];

    char* p = (char*)d_ws;
    auto alloc = [&](size_t bytes) { void* r = (void*)p; p += ((bytes + 255) / 256) * 256; return r; };
    int*   flags = (int*)  alloc(256);
    bf16*  X1t   = (bf16*) alloc((size_t)320 * NND * 2);     // emb^T, padded to 320 rows
    bf16*  X2t   = (bf16*) alloc((size_t)1280 * NND * 2);    // x2^T, padded to 1280 rows
    bf16*  x2    = (bf16*) alloc((size_t)NND * F2 * 2);
    bf16*  cc4   = (bf16*) alloc((size_t)HH * NND * 2 * DD * 2);
    bf16*  ccO   = (bf16*) alloc((size_t)NND * 2 * F2 * 2);
    bf16*  wtT4  = (bf16*) alloc((size_t)HH * DD * 2 * DD * 2);
    bf16*  wtTo  = (bf16*) alloc((size_t)DD * 2 * F2 * 2);
    bf16*  ofull = (bf16*) alloc((size_t)NND * DD * 2);
    float* uh1   = (float*)alloc((size_t)HH * DD * 4);
    float* uh2   = (float*)alloc((size_t)HH * DD * 4);
    float* uo1   = (float*)alloc((size_t)F2 * 4);
    float* uo2   = (float*)alloc((size_t)F2 * 4);
    float* Wh1h  = (float*)alloc((size_t)HH * NND * 4);
    float* Wh2h  = (float*)alloc((size_t)HH * NND * 4);
    float* Wh1o  = (float*)alloc((size_t)NND * 4);
    float* Wh2o  = (float*)alloc((size_t)NND * 4);
    float* rsph  = (float*)alloc((size_t)HH * NND * 4);
    float* rsnh  = (float*)alloc((size_t)HH * NND * 4);
    float* rspo  = (float*)alloc((size_t)NND * 4);
    float* rsno  = (float*)alloc((size_t)NND * 4);

    dim3 tb(32, 8);
    k_detect<<<1, 64, 0, stream>>>(emb, adj, flags);
    hipMemsetAsync(X1t, 0, (size_t)320 * NND * 2, stream);
    hipMemsetAsync(X2t, 0, (size_t)1280 * NND * 2, stream);
    // X1t = emb^T: [R=3072][C=300] -> grid (10, 96)
    k_transpose<<<dim3((DD + 31) / 32, (NND + 31) / 32), tb, 0, stream>>>(emb, 0, X1t, NND, DD, flags, 1);
    k_uvec<<<dim3((DD + 3) / 4, HH), 256, 0, stream>>>(Whd, ahd, uh1, uh2, DD, DD,
                                                       (long)DD * DD, (long)2 * DD, DD, flags);
    k_gemv2<<<dim3(NND / 4, HH), 256, 0, stream>>>(emb, uh1, uh2, Wh1h, Wh2h, NND, DD, DD, NND, flags, 1);
    k_stats<<<dim3(NND, HH), 256, 0, stream>>>(Wh1h, Wh2h, NND, adj, flags, rsph, rsnh);
    // all 4 heads' fused attention GEMM in one dispatch: grid (2, 96, 4) = 768 blocks
    k_fattgemm<<<dim3(2, 96, HH), 256, 0, stream>>>(Wh1h, Wh2h, rsph, rsnh, NND,
                                                    adj, flags, X1t, cc4,
                                                    (long)NND * 2 * DD, 2 * DD, DD);
    // wth block is [R=600][C=300] -> grid (10, 19)
    for (int l = 0; l < HH; l++)
        k_transpose<<<dim3((DD + 31) / 32, (2 * DD + 31) / 32), tb, 0, stream>>>(
            wth, (size_t)l * 2 * DD * DD, wtT4 + (size_t)l * DD * 2 * DD, 2 * DD, DD, flags, 1);
    // head-batched concat GEMM with ELU -> x2 column blocks: grid (5, 96, 4)
    k_ccgemm<<<dim3(5, 96, HH), 256, 0, stream>>>(cc4, wtT4, x2, 2 * DD, DD, F2, 0, 0,
                                                  (long)NND * 2 * DD, (long)DD * 2 * DD, DD);
    // output layer
    k_transpose<<<dim3((F2 + 31) / 32, (NND + 31) / 32), tb, 0, stream>>>(x2, 0, X2t, NND, F2, flags, 0);
    k_uvec<<<dim3((F2 + 3) / 4, 1), 256, 0, stream>>>(Wo, ao, uo1, uo2, F2, DD, 0, 0, 0, flags);
    k_gemv2<<<dim3(NND / 4, 1), 256, 0, stream>>>(x2, uo1, uo2, Wh1o, Wh2o, NND, F2, 0, 0, flags, 0);
    k_stats<<<dim3(NND, 1), 256, 0, stream>>>(Wh1o, Wh2o, 0, adj, flags, rspo, rsno);
    // output fused attention GEMM: grid (8, 96, 1) = 768 blocks
    k_fattgemm<<<dim3(8, 96, 1), 256, 0, stream>>>(Wh1o, Wh2o, rspo, rsno, 0,
                                                   adj, flags, X2t, ccO, 0, 2 * F2, F2);
    // wto is [R=2400][C=300] -> grid (10, 75)
    k_transpose<<<dim3((DD + 31) / 32, (2 * F2 + 31) / 32), tb, 0, stream>>>(wto, 0, wtTo, 2 * F2, DD, flags, 1);
    k_ccgemm<<<dim3(5, 96, 1), 256, 0, stream>>>(ccO, wtTo, ofull, 2 * F2, DD, DD, 0, 1, 0, 0, 0);
    k_gather<<<(64 * DD + 255) / 256, 256, 0, stream>>>(ofull, tid, d_out, flags);
}

// Round 7
// 541.687 us; speedup vs baseline: 1.1579x; 1.1579x over previous
//
#include <hip/hip_runtime.h>
#include <hip/hip_bf16.h>
#include <stdint.h>

#define NND 3072
#define NB8 (NND / 8)      // adjbits row bytes = 384
#define DD 300
#define HH 4
#define F2 1200
#define TNC 40             // ccgemm LDS pad (32 + 8)
#define MREP 10            // fatt2 feature sub-tiles per wave (160 features)
#define PANEL (MREP * 16)

typedef __attribute__((ext_vector_type(8))) short short8v;
typedef __attribute__((ext_vector_type(4))) float f32x4;
typedef __hip_bfloat16 bf16;

__device__ inline float ldin(const void* p, size_t i, int isf32) {
    return isf32 ? ((const float*)p)[i]
                 : __bfloat162float(((const bf16*)p)[i]);
}

__device__ inline ushort f2bf(float x) {
    bf16 t = __float2bfloat16(x);
    return *reinterpret_cast<ushort*>(&t);
}

__device__ inline uint pack2(float lo, float hi) {
    return (uint)f2bf(lo) | ((uint)f2bf(hi) << 16);
}

// ---- dtype sniffer: flags[0]=1 iff float inputs are f32; flags[1]=1 iff adj is int32
__global__ void k_detect(const void* emb, const void* adj, int* flags) {
    if (threadIdx.x == 0 && blockIdx.x == 0) {
        const uint16_t* u = (const uint16_t*)emb;
        int plaus = 0;
        for (int i = 0; i < 128; i++) {
            int e = (u[i] >> 7) & 0xFF;
            if (e >= 112 && e <= 143) plaus++;
        }
        flags[0] = (plaus < 100) ? 1 : 0;
        const uint8_t* b = (const uint8_t*)adj;
        int nz = 0;
        for (int i = 0; i < 256; i++) if ((i & 3) != 0 && b[i]) nz++;
        flags[1] = (nz == 0) ? 1 : 0;
    }
}

// ---- pack adjacency to 1 bit per entry: adjbits[i][j/8]
__global__ void k_adjpack(const void* adj, const int* flags, uint8_t* bits) {
    int i = blockIdx.x, o = threadIdx.x;          // o = byte index 0..383 (8 j's each)
    int adjInt = flags[1];
    uint8_t b = 0;
    if (!adjInt) {
        const uint8_t* row = (const uint8_t*)adj + (size_t)i * NND + o * 8;
        uint2 v = *(const uint2*)row;
        #pragma unroll
        for (int jj = 0; jj < 4; jj++) {
            if ((v.x >> (8 * jj)) & 0xffu) b |= 1u << jj;
            if ((v.y >> (8 * jj)) & 0xffu) b |= 1u << (4 + jj);
        }
    } else {
        const int* row = (const int*)adj + (size_t)i * NND + o * 8;
        int4 u = *(const int4*)row;
        int4 v = *(const int4*)(row + 4);
        if (u.x) b |= 1;  if (u.y) b |= 2;   if (u.z) b |= 4;   if (u.w) b |= 8;
        if (v.x) b |= 16; if (v.y) b |= 32;  if (v.z) b |= 64;  if (v.w) b |= 128;
    }
    bits[(size_t)i * NB8 + o] = b;
}

// ---- T[c][r] = A[r][c], output bf16.  grid = ((C+31)/32, (R+31)/32)
__global__ void k_transpose(const void* A, size_t baseOff, bf16* T, int R, int C,
                            const int* flags, int useFlag) {
    __shared__ bf16 t[32][33];
    int isf = useFlag ? flags[0] : 0;
    int rt = blockIdx.y * 32, ct = blockIdx.x * 32;
    int tx = threadIdx.x, ty = threadIdx.y;
    for (int i = 0; i < 4; i++) {
        int r = rt + ty + 8 * i, c = ct + tx;
        if (r < R && c < C)
            t[ty + 8 * i][tx] = __float2bfloat16(ldin(A, baseOff + (size_t)r * C + c, isf));
    }
    __syncthreads();
    for (int i = 0; i < 4; i++) {
        int c = ct + ty + 8 * i, r = rt + tx;
        if (c < C && r < R) T[(size_t)c * R + r] = t[tx][ty + 8 * i];
    }
}

// ---- u1 = W @ a[:C], u2 = W @ a[C:2C]
__global__ void k_uvec(const void* W, const void* a, float* u1, float* u2, int R, int C,
                       long Wb, long ab, long ub, const int* flags) {
    int isf = flags[0];
    int h = blockIdx.y;
    int wid = threadIdx.x >> 6, lane = threadIdx.x & 63;
    int r = blockIdx.x * 4 + wid;
    if (r >= R) return;
    float s1 = 0.f, s2 = 0.f;
    for (int c = lane; c < C; c += 64) {
        float w = ldin(W, (size_t)h * Wb + (size_t)r * C + c, isf);
        s1 += w * ldin(a, (size_t)h * ab + c, isf);
        s2 += w * ldin(a, (size_t)h * ab + C + c, isf);
    }
    for (int o = 32; o; o >>= 1) { s1 += __shfl_down(s1, o); s2 += __shfl_down(s2, o); }
    if (lane == 0) { u1[(size_t)h * ub + r] = s1; u2[(size_t)h * ub + r] = s2; }
}

// ---- o1[i] = X[i,:]·u1, o2[i] = X[i,:]·u2
__global__ void k_gemv2(const void* X, const float* u1, const float* u2, float* o1, float* o2,
                        int M, int K, long ub, long ob, const int* flags, int useFlag) {
    int isf = useFlag ? flags[0] : 0;
    int h = blockIdx.y;
    const float* U1 = u1 + (size_t)h * ub;
    const float* U2 = u2 + (size_t)h * ub;
    int wid = threadIdx.x >> 6, lane = threadIdx.x & 63;
    int row = blockIdx.x * 4 + wid;
    if (row >= M) return;
    float s1 = 0.f, s2 = 0.f;
    for (int k = lane; k < K; k += 64) {
        float x = ldin(X, (size_t)row * K + k, isf);
        s1 += x * U1[k]; s2 += x * U2[k];
    }
    for (int o = 32; o; o >>= 1) { s1 += __shfl_down(s1, o); s2 += __shfl_down(s2, o); }
    if (lane == 0) { o1[(size_t)h * ob + row] = s1; o2[(size_t)h * ob + row] = s2; }
}

// ---- fused attention GEMM, operand-swapped: D[f][i] = sum_j Xt[f][j] * P^T[j][i].
// P built in-register in the exact MFMA B-fragment layout (lane&15 -> i,
// (lane>>4)*8 -> j-octet). No LDS, no barriers. Row softmax sums accumulated
// in-wave (2 shfl_xor at the end). Each wave: one 160-feature panel x 32 i's,
// both signs. Writes CC[i][side*F + f] scaled by 1/sum.
__global__ __launch_bounds__(128, 2) void k_fatt2(
    const float* __restrict__ Wh1A, const float* __restrict__ Wh2A, long hs,
    const uint8_t* __restrict__ adjbits,
    const bf16* __restrict__ Xt,           // [rowsPad][NND] feature-major, zero-padded
    bf16* __restrict__ CC, long ccHeadStride, int ccStride, int F) {
    int h = blockIdx.z;
    const float* Wh1 = Wh1A + (size_t)h * hs;
    const float* Wh2 = Wh2A + (size_t)h * hs;
    bf16* C = CC + (size_t)h * ccHeadStride;
    int w = threadIdx.x >> 6, lane = threadIdx.x & 63;
    int fbase = blockIdx.y * PANEL;
    int ibase = (blockIdx.x * 2 + w) * 32;
    int i1 = ibase + (lane & 15), i2 = i1 + 16;
    int ksh = (lane >> 4) * 8;             // k-octet offset within 32-k step
    float w1a = Wh1[i1], w1b = Wh1[i2];
    const uint8_t* ab1 = adjbits + (size_t)i1 * NB8;
    const uint8_t* ab2 = adjbits + (size_t)i2 * NB8;
    const bf16* Abase = Xt + (size_t)(fbase + (lane & 15)) * NND + ksh;
    f32x4 acc[MREP][2][2] = {};            // [m][itile][side]
    float sp1 = 0.f, sn1 = 0.f, sp2 = 0.f, sn2 = 0.f;

    for (int k0 = 0; k0 < NND; k0 += 32) {
        uint m1 = *(const uint*)(ab1 + (k0 >> 3));
        uint m2 = *(const uint*)(ab2 + (k0 >> 3));
        float4 wa = *(const float4*)(Wh2 + k0 + ksh);
        float4 wb = *(const float4*)(Wh2 + k0 + ksh + 4);
        float zs0 = wa.x, zs1 = wa.y, zs2 = wa.z, zs3 = wa.w;
        float zs4 = wb.x, zs5 = wb.y, zs6 = wb.z, zs7 = wb.w;
        short8v bp1, bq1, bp2, bq2;
        #pragma unroll
        for (int jj = 0; jj < 8; jj++) {
            float zj = (jj == 0) ? zs0 : (jj == 1) ? zs1 : (jj == 2) ? zs2 : (jj == 3) ? zs3
                     : (jj == 4) ? zs4 : (jj == 5) ? zs5 : (jj == 6) ? zs6 : zs7;
            bool on1 = (m1 >> (ksh + jj)) & 1u;
            bool on2 = (m2 >> (ksh + jj)) & 1u;
            float z1 = w1a + zj;
            float e1 = fmaxf(z1, 0.3f * z1);
            float pe1 = on1 ? __expf(e1) : 0.0f;
            float qe1 = on1 ? __expf(-e1) : 0.0f;
            float z2 = w1b + zj;
            float e2 = fmaxf(z2, 0.3f * z2);
            float pe2 = on2 ? __expf(e2) : 0.0f;
            float qe2 = on2 ? __expf(-e2) : 0.0f;
            sp1 += pe1; sn1 += qe1; sp2 += pe2; sn2 += qe2;
            bp1[jj] = (short)f2bf(pe1); bq1[jj] = (short)f2bf(qe1);
            bp2[jj] = (short)f2bf(pe2); bq2[jj] = (short)f2bf(qe2);
        }
        #pragma unroll
        for (int m = 0; m < MREP; m++) {
            short8v a = *(const short8v*)(Abase + (size_t)m * 16 * NND + k0);
            acc[m][0][0] = __builtin_amdgcn_mfma_f32_16x16x32_bf16(a, bp1, acc[m][0][0], 0, 0, 0);
            acc[m][0][1] = __builtin_amdgcn_mfma_f32_16x16x32_bf16(a, bq1, acc[m][0][1], 0, 0, 0);
            acc[m][1][0] = __builtin_amdgcn_mfma_f32_16x16x32_bf16(a, bp2, acc[m][1][0], 0, 0, 0);
            acc[m][1][1] = __builtin_amdgcn_mfma_f32_16x16x32_bf16(a, bq2, acc[m][1][1], 0, 0, 0);
        }
    }
    // full row sums: partials live on lanes sharing (lane&15); reduce over lane^16, lane^32
    sp1 += __shfl_xor(sp1, 16); sp1 += __shfl_xor(sp1, 32);
    sn1 += __shfl_xor(sn1, 16); sn1 += __shfl_xor(sn1, 32);
    sp2 += __shfl_xor(sp2, 16); sp2 += __shfl_xor(sp2, 32);
    sn2 += __shfl_xor(sn2, 16); sn2 += __shfl_xor(sn2, 32);
    float sc1[2] = { 1.0f / sp1, -1.0f / sn1 };
    float sc2[2] = { 1.0f / sp2, -1.0f / sn2 };
    int fo = (lane >> 4) * 4;
    bf16* crow1 = C + (size_t)i1 * ccStride;
    bf16* crow2 = C + (size_t)i2 * ccStride;
    #pragma unroll
    for (int m = 0; m < MREP; m++) {
        int fc = fbase + m * 16 + fo;
        if (fc >= F) continue;
        #pragma unroll
        for (int side = 0; side < 2; side++) {
            uint2 u1v, u2v;
            u1v.x = pack2(acc[m][0][side][0] * sc1[side], acc[m][0][side][1] * sc1[side]);
            u1v.y = pack2(acc[m][0][side][2] * sc1[side], acc[m][0][side][3] * sc1[side]);
            u2v.x = pack2(acc[m][1][side][0] * sc2[side], acc[m][1][side][1] * sc2[side]);
            u2v.y = pack2(acc[m][1][side][2] * sc2[side], acc[m][1][side][3] * sc2[side]);
            *(uint2*)(crow1 + side * F + fc) = u1v;
            *(uint2*)(crow2 + side * F + fc) = u2v;
        }
    }
}

// ---- Out[:,off:off+N] = epi(A @ Bt^T); M-tile 32, N-tile 64; head-batched via blockIdx.z
__global__ __launch_bounds__(256) void k_ccgemm(const bf16* __restrict__ A0, const bf16* __restrict__ Bt0,
                                                bf16* __restrict__ Out, int K, int Ncols,
                                                int outStride, int outColOff0, int mode,
                                                long aHeadStride, long btHeadStride, int outColStep) {
    __shared__ __align__(16) bf16 Alds[32 * TNC];
    __shared__ __align__(16) bf16 Blds[64 * TNC];
    int h = blockIdx.z;
    const bf16* A = A0 + (size_t)h * aHeadStride;
    const bf16* Bt = Bt0 + (size_t)h * btHeadStride;
    int outColOff = outColOff0 + h * outColStep;
    int tid = threadIdx.x, lane = tid & 63, w = tid >> 6, wr = w >> 1, wc = w & 1;
    int m0 = blockIdx.y * 32, n0 = blockIdx.x * 64;
    int smA = tid >> 3, skA = (tid & 7) * 4;
    int smB = tid >> 2, skB = (tid & 3) * 8;
    f32x4 acc[2] = {};
    for (int k0 = 0; k0 < K; k0 += 32) {
        uint2 va = make_uint2(0, 0);
        uint4 vx = make_uint4(0, 0, 0, 0);
        if (k0 + skA < K) va = *(const uint2*)(A + (size_t)(m0 + smA) * K + k0 + skA);
        if (n0 + smB < Ncols && k0 + skB < K) vx = *(const uint4*)(Bt + (size_t)(n0 + smB) * K + k0 + skB);
        __syncthreads();
        *(uint2*)&Alds[smA * TNC + skA] = va;
        *(uint4*)&Blds[smB * TNC + skB] = vx;
        __syncthreads();
        int arr = wr * 16 + (lane & 15), koff = (lane >> 4) * 8;
        int br = wc * 32 + (lane & 15);
        short8v a0 = *(const short8v*)&Alds[arr * TNC + koff];
        short8v b0 = *(const short8v*)&Blds[br * TNC + koff];
        short8v b1 = *(const short8v*)&Blds[(br + 16) * TNC + koff];
        acc[0] = __builtin_amdgcn_mfma_f32_16x16x32_bf16(a0, b0, acc[0], 0, 0, 0);
        acc[1] = __builtin_amdgcn_mfma_f32_16x16x32_bf16(a0, b1, acc[1], 0, 0, 0);
    }
    for (int ni = 0; ni < 2; ni++) {
        int col = n0 + wc * 32 + ni * 16 + (lane & 15);
        if (col >= Ncols) continue;
        int rbase = m0 + wr * 16 + (lane >> 4) * 4;
        for (int r = 0; r < 4; r++) {
            float v = acc[ni][r];
            if (mode == 0) v = v > 0.f ? v : (__expf(v) - 1.0f);
            else           v = 1.0f / (1.0f + __expf(-v));
            Out[(size_t)(rbase + r) * outStride + outColOff + col] = __float2bfloat16(v);
        }
    }
}

__global__ void k_gather(const bf16* full, const int* ids, void* out, const int* flags) {
    int idx = blockIdx.x * 256 + threadIdx.x;
    if (idx >= 64 * DD) return;
    int t = idx / DD, d = idx - t * DD;
    float v = __bfloat162float(full[(size_t)ids[t] * DD + d]);
    if (flags[0]) ((float*)out)[idx] = v;
    else ((bf16*)out)[idx] = __float2bfloat16(v);
}

extern "C" void kernel_launch(void* const* d_in, const int* in_sizes, int n_in,
                              void* d_out, int out_size, void* d_ws, size_t ws_size,
                              hipStream_t stream) {
    const void* emb = d_in[0];
    const void* Whd = d_in[1];
    const void* ahd = d_in[2];
    const void* wth = d_in[3];
    const void* Wo  = d_in[4];
    const void* ao  = d_in[5];
    const void* wto = d_in[6];
    const void* adj = d_in[7];
    const int* tid  = (const int*)d_in[8];

    char* p = (char*)d_ws;
    auto alloc = [&](size_t bytes) { void* r = (void*)p; p += ((bytes + 255) / 256) * 256; return r; };
    int*     flags   = (int*)    alloc(256);
    uint8_t* adjbits = (uint8_t*)alloc((size_t)NND * NB8);
    bf16*  X1t   = (bf16*) alloc((size_t)320 * NND * 2);     // emb^T, padded to 320 rows
    bf16*  X2t   = (bf16*) alloc((size_t)1280 * NND * 2);    // x2^T, padded to 1280 rows
    bf16*  x2    = (bf16*) alloc((size_t)NND * F2 * 2);
    bf16*  cc4   = (bf16*) alloc((size_t)HH * NND * 2 * DD * 2);
    bf16*  ccO   = (bf16*) alloc((size_t)NND * 2 * F2 * 2);
    bf16*  wtT4  = (bf16*) alloc((size_t)HH * DD * 2 * DD * 2);
    bf16*  wtTo  = (bf16*) alloc((size_t)DD * 2 * F2 * 2);
    bf16*  ofull = (bf16*) alloc((size_t)NND * DD * 2);
    float* uh1   = (float*)alloc((size_t)HH * DD * 4);
    float* uh2   = (float*)alloc((size_t)HH * DD * 4);
    float* uo1   = (float*)alloc((size_t)F2 * 4);
    float* uo2   = (float*)alloc((size_t)F2 * 4);
    float* Wh1h  = (float*)alloc((size_t)HH * NND * 4);
    float* Wh2h  = (float*)alloc((size_t)HH * NND * 4);
    float* Wh1o  = (float*)alloc((size_t)NND * 4);
    float* Wh2o  = (float*)alloc((size_t)NND * 4);

    dim3 tb(32, 8);
    k_detect<<<1, 64, 0, stream>>>(emb, adj, flags);
    k_adjpack<<<NND, NB8, 0, stream>>>(adj, flags, adjbits);
    hipMemsetAsync(X1t, 0, (size_t)320 * NND * 2, stream);
    hipMemsetAsync(X2t, 0, (size_t)1280 * NND * 2, stream);
    // X1t = emb^T: [R=3072][C=300] -> grid (10, 96)
    k_transpose<<<dim3((DD + 31) / 32, (NND + 31) / 32), tb, 0, stream>>>(emb, 0, X1t, NND, DD, flags, 1);
    k_uvec<<<dim3((DD + 3) / 4, HH), 256, 0, stream>>>(Whd, ahd, uh1, uh2, DD, DD,
                                                       (long)DD * DD, (long)2 * DD, DD, flags);
    k_gemv2<<<dim3(NND / 4, HH), 256, 0, stream>>>(emb, uh1, uh2, Wh1h, Wh2h, NND, DD, DD, NND, flags, 1);
    // heads fused attention GEMM (operand-swapped, no LDS/barriers):
    // grid (i-groups=48, panels=2, heads=4) = 384 blocks x 128 threads
    k_fatt2<<<dim3(48, 2, HH), 128, 0, stream>>>(Wh1h, Wh2h, NND, adjbits, X1t, cc4,
                                                 (long)NND * 2 * DD, 2 * DD, DD);
    // wth block is [R=600][C=300] -> grid (10, 19)
    for (int l = 0; l < HH; l++)
        k_transpose<<<dim3((DD + 31) / 32, (2 * DD + 31) / 32), tb, 0, stream>>>(
            wth, (size_t)l * 2 * DD * DD, wtT4 + (size_t)l * DD * 2 * DD, 2 * DD, DD, flags, 1);
    // head-batched concat GEMM with ELU -> x2 column blocks: grid (5, 96, 4)
    k_ccgemm<<<dim3(5, 96, HH), 256, 0, stream>>>(cc4, wtT4, x2, 2 * DD, DD, F2, 0, 0,
                                                  (long)NND * 2 * DD, (long)DD * 2 * DD, DD);
    // output layer
    k_transpose<<<dim3((F2 + 31) / 32, (NND + 31) / 32), tb, 0, stream>>>(x2, 0, X2t, NND, F2, flags, 0);
    k_uvec<<<dim3((F2 + 3) / 4, 1), 256, 0, stream>>>(Wo, ao, uo1, uo2, F2, DD, 0, 0, 0, flags);
    k_gemv2<<<dim3(NND / 4, 1), 256, 0, stream>>>(x2, uo1, uo2, Wh1o, Wh2o, NND, F2, 0, 0, flags, 0);
    // output fused attention GEMM: grid (48, 8, 1) = 384 blocks
    k_fatt2<<<dim3(48, 8, 1), 128, 0, stream>>>(Wh1o, Wh2o, 0, adjbits, X2t, ccO,
                                                0, 2 * F2, F2);
    // wto is [R=2400][C=300] -> grid (10, 75)
    k_transpose<<<dim3((DD + 31) / 32, (2 * F2 + 31) / 32), tb, 0, stream>>>(wto, 0, wtTo, 2 * F2, DD, flags, 1);
    k_ccgemm<<<dim3(5, 96, 1), 256, 0, stream>>>(ccO, wtTo, ofull, 2 * F2, DD, DD, 0, 1, 0, 0, 0);
    k_gather<<<(64 * DD + 255) / 256, 256, 0, stream>>>(ofull, tid, d_out, flags);
}

// Round 8
// 470.460 us; speedup vs baseline: 1.3332x; 1.1514x over previous
//
#include <hip/hip_runtime.h>
#include <hip/hip_bf16.h>
#include <stdint.h>

#define NND 3072
#define NB8 (NND / 8)      // adjbits row bytes = 384
#define DD 300
#define HH 4
#define F2 1200
#define TNC 40             // ccgemm LDS pad (32 + 8)
#define MREP 5             // fatt2 feature sub-tiles per wave (80 features)
#define PANEL (MREP * 16)

typedef __attribute__((ext_vector_type(8))) short short8v;
typedef __attribute__((ext_vector_type(4))) float f32x4;
typedef __hip_bfloat16 bf16;

__device__ inline float ldin(const void* p, size_t i, int isf32) {
    return isf32 ? ((const float*)p)[i]
                 : __bfloat162float(((const bf16*)p)[i]);
}

__device__ inline ushort f2bf(float x) {
    bf16 t = __float2bfloat16(x);
    return *reinterpret_cast<ushort*>(&t);
}

__device__ inline uint pack2(float lo, float hi) {
    return (uint)f2bf(lo) | ((uint)f2bf(hi) << 16);
}

// ---- dtype sniffer: flags[0]=1 iff float inputs are f32; flags[1]=1 iff adj is int32
__global__ void k_detect(const void* emb, const void* adj, int* flags) {
    if (threadIdx.x == 0 && blockIdx.x == 0) {
        const uint16_t* u = (const uint16_t*)emb;
        int plaus = 0;
        for (int i = 0; i < 128; i++) {
            int e = (u[i] >> 7) & 0xFF;
            if (e >= 112 && e <= 143) plaus++;
        }
        flags[0] = (plaus < 100) ? 1 : 0;
        const uint8_t* b = (const uint8_t*)adj;
        int nz = 0;
        for (int i = 0; i < 256; i++) if ((i & 3) != 0 && b[i]) nz++;
        flags[1] = (nz == 0) ? 1 : 0;
    }
}

// ---- pack adjacency to 1 bit per entry: adjbits[i][j/8]
__global__ void k_adjpack(const void* adj, const int* flags, uint8_t* bits) {
    int i = blockIdx.x, o = threadIdx.x;          // o = byte index 0..383 (8 j's each)
    int adjInt = flags[1];
    uint8_t b = 0;
    if (!adjInt) {
        const uint8_t* row = (const uint8_t*)adj + (size_t)i * NND + o * 8;
        uint2 v = *(const uint2*)row;
        #pragma unroll
        for (int jj = 0; jj < 4; jj++) {
            if ((v.x >> (8 * jj)) & 0xffu) b |= 1u << jj;
            if ((v.y >> (8 * jj)) & 0xffu) b |= 1u << (4 + jj);
        }
    } else {
        const int* row = (const int*)adj + (size_t)i * NND + o * 8;
        int4 u = *(const int4*)row;
        int4 v = *(const int4*)(row + 4);
        if (u.x) b |= 1;  if (u.y) b |= 2;   if (u.z) b |= 4;   if (u.w) b |= 8;
        if (v.x) b |= 16; if (v.y) b |= 32;  if (v.z) b |= 64;  if (v.w) b |= 128;
    }
    bits[(size_t)i * NB8 + o] = b;
}

// ---- T[c][r] = A[r][c], output bf16.  grid = ((C+31)/32, (R+31)/32)
__global__ void k_transpose(const void* A, size_t baseOff, bf16* T, int R, int C,
                            const int* flags, int useFlag) {
    __shared__ bf16 t[32][33];
    int isf = useFlag ? flags[0] : 0;
    int rt = blockIdx.y * 32, ct = blockIdx.x * 32;
    int tx = threadIdx.x, ty = threadIdx.y;
    for (int i = 0; i < 4; i++) {
        int r = rt + ty + 8 * i, c = ct + tx;
        if (r < R && c < C)
            t[ty + 8 * i][tx] = __float2bfloat16(ldin(A, baseOff + (size_t)r * C + c, isf));
    }
    __syncthreads();
    for (int i = 0; i < 4; i++) {
        int c = ct + ty + 8 * i, r = rt + tx;
        if (c < C && r < R) T[(size_t)c * R + r] = t[tx][ty + 8 * i];
    }
}

// ---- u1 = W @ a[:C], u2 = W @ a[C:2C]
__global__ void k_uvec(const void* W, const void* a, float* u1, float* u2, int R, int C,
                       long Wb, long ab, long ub, const int* flags) {
    int isf = flags[0];
    int h = blockIdx.y;
    int wid = threadIdx.x >> 6, lane = threadIdx.x & 63;
    int r = blockIdx.x * 4 + wid;
    if (r >= R) return;
    float s1 = 0.f, s2 = 0.f;
    for (int c = lane; c < C; c += 64) {
        float w = ldin(W, (size_t)h * Wb + (size_t)r * C + c, isf);
        s1 += w * ldin(a, (size_t)h * ab + c, isf);
        s2 += w * ldin(a, (size_t)h * ab + C + c, isf);
    }
    for (int o = 32; o; o >>= 1) { s1 += __shfl_down(s1, o); s2 += __shfl_down(s2, o); }
    if (lane == 0) { u1[(size_t)h * ub + r] = s1; u2[(size_t)h * ub + r] = s2; }
}

// ---- o1[i] = X[i,:]·u1, o2[i] = X[i,:]·u2
__global__ void k_gemv2(const void* X, const float* u1, const float* u2, float* o1, float* o2,
                        int M, int K, long ub, long ob, const int* flags, int useFlag) {
    int isf = useFlag ? flags[0] : 0;
    int h = blockIdx.y;
    const float* U1 = u1 + (size_t)h * ub;
    const float* U2 = u2 + (size_t)h * ub;
    int wid = threadIdx.x >> 6, lane = threadIdx.x & 63;
    int row = blockIdx.x * 4 + wid;
    if (row >= M) return;
    float s1 = 0.f, s2 = 0.f;
    for (int k = lane; k < K; k += 64) {
        float x = ldin(X, (size_t)row * K + k, isf);
        s1 += x * U1[k]; s2 += x * U2[k];
    }
    for (int o = 32; o; o >>= 1) { s1 += __shfl_down(s1, o); s2 += __shfl_down(s2, o); }
    if (lane == 0) { o1[(size_t)h * ob + row] = s1; o2[(size_t)h * ob + row] = s2; }
}

// ---- fused attention GEMM, operand-swapped: D[f][i] = sum_j Xt[f][j] * P^T[j][i].
// P built in-register in the exact MFMA B-fragment layout (lane&15 -> i,
// (lane>>4)*8 -> j-octet). No LDS, no barriers. Row softmax sums accumulated
// in-wave (2 shfl_xor at the end). Each wave: one 80-feature panel x 32 i's,
// both signs (acc = 80 VGPRs; small footprint -> loads stay in flight).
__global__ __launch_bounds__(128, 2) void k_fatt2(
    const float* __restrict__ Wh1A, const float* __restrict__ Wh2A, long hs,
    const uint8_t* __restrict__ adjbits,
    const bf16* __restrict__ Xt,           // [rowsPad][NND] feature-major, zero-padded
    bf16* __restrict__ CC, long ccHeadStride, int ccStride, int F) {
    int h = blockIdx.z;
    const float* Wh1 = Wh1A + (size_t)h * hs;
    const float* Wh2 = Wh2A + (size_t)h * hs;
    bf16* C = CC + (size_t)h * ccHeadStride;
    int w = threadIdx.x >> 6, lane = threadIdx.x & 63;
    int fbase = blockIdx.y * PANEL;
    int ibase = (blockIdx.x * 2 + w) * 32;
    int i1 = ibase + (lane & 15), i2 = i1 + 16;
    int ksh = (lane >> 4) * 8;             // k-octet offset within 32-k step
    float w1a = Wh1[i1], w1b = Wh1[i2];
    const uint8_t* ab1 = adjbits + (size_t)i1 * NB8;
    const uint8_t* ab2 = adjbits + (size_t)i2 * NB8;
    const bf16* Abase = Xt + (size_t)(fbase + (lane & 15)) * NND + ksh;
    f32x4 acc[MREP][2][2] = {};            // [m][itile][side]
    float sp1 = 0.f, sn1 = 0.f, sp2 = 0.f, sn2 = 0.f;

    for (int k0 = 0; k0 < NND; k0 += 32) {
        uint m1 = *(const uint*)(ab1 + (k0 >> 3));
        uint m2 = *(const uint*)(ab2 + (k0 >> 3));
        float4 wa = *(const float4*)(Wh2 + k0 + ksh);
        float4 wb = *(const float4*)(Wh2 + k0 + ksh + 4);
        float zs0 = wa.x, zs1 = wa.y, zs2 = wa.z, zs3 = wa.w;
        float zs4 = wb.x, zs5 = wb.y, zs6 = wb.z, zs7 = wb.w;
        short8v bp1, bq1, bp2, bq2;
        #pragma unroll
        for (int jj = 0; jj < 8; jj++) {
            float zj = (jj == 0) ? zs0 : (jj == 1) ? zs1 : (jj == 2) ? zs2 : (jj == 3) ? zs3
                     : (jj == 4) ? zs4 : (jj == 5) ? zs5 : (jj == 6) ? zs6 : zs7;
            bool on1 = (m1 >> (ksh + jj)) & 1u;
            bool on2 = (m2 >> (ksh + jj)) & 1u;
            float z1 = w1a + zj;
            float e1 = fmaxf(z1, 0.3f * z1);
            float pe1 = on1 ? __expf(e1) : 0.0f;
            float qe1 = on1 ? __expf(-e1) : 0.0f;
            float z2 = w1b + zj;
            float e2 = fmaxf(z2, 0.3f * z2);
            float pe2 = on2 ? __expf(e2) : 0.0f;
            float qe2 = on2 ? __expf(-e2) : 0.0f;
            sp1 += pe1; sn1 += qe1; sp2 += pe2; sn2 += qe2;
            bp1[jj] = (short)f2bf(pe1); bq1[jj] = (short)f2bf(qe1);
            bp2[jj] = (short)f2bf(pe2); bq2[jj] = (short)f2bf(qe2);
        }
        #pragma unroll
        for (int m = 0; m < MREP; m++) {
            short8v a = *(const short8v*)(Abase + (size_t)m * 16 * NND + k0);
            acc[m][0][0] = __builtin_amdgcn_mfma_f32_16x16x32_bf16(a, bp1, acc[m][0][0], 0, 0, 0);
            acc[m][0][1] = __builtin_amdgcn_mfma_f32_16x16x32_bf16(a, bq1, acc[m][0][1], 0, 0, 0);
            acc[m][1][0] = __builtin_amdgcn_mfma_f32_16x16x32_bf16(a, bp2, acc[m][1][0], 0, 0, 0);
            acc[m][1][1] = __builtin_amdgcn_mfma_f32_16x16x32_bf16(a, bq2, acc[m][1][1], 0, 0, 0);
        }
    }
    // full row sums: partials live on lanes sharing (lane&15); reduce over lane^16, lane^32
    sp1 += __shfl_xor(sp1, 16); sp1 += __shfl_xor(sp1, 32);
    sn1 += __shfl_xor(sn1, 16); sn1 += __shfl_xor(sn1, 32);
    sp2 += __shfl_xor(sp2, 16); sp2 += __shfl_xor(sp2, 32);
    sn2 += __shfl_xor(sn2, 16); sn2 += __shfl_xor(sn2, 32);
    float sc1[2] = { 1.0f / sp1, -1.0f / sn1 };
    float sc2[2] = { 1.0f / sp2, -1.0f / sn2 };
    int fo = (lane >> 4) * 4;
    bf16* crow1 = C + (size_t)i1 * ccStride;
    bf16* crow2 = C + (size_t)i2 * ccStride;
    #pragma unroll
    for (int m = 0; m < MREP; m++) {
        int fc = fbase + m * 16 + fo;
        if (fc >= F) continue;
        #pragma unroll
        for (int side = 0; side < 2; side++) {
            uint2 u1v, u2v;
            u1v.x = pack2(acc[m][0][side][0] * sc1[side], acc[m][0][side][1] * sc1[side]);
            u1v.y = pack2(acc[m][0][side][2] * sc1[side], acc[m][0][side][3] * sc1[side]);
            u2v.x = pack2(acc[m][1][side][0] * sc2[side], acc[m][1][side][1] * sc2[side]);
            u2v.y = pack2(acc[m][1][side][2] * sc2[side], acc[m][1][side][3] * sc2[side]);
            *(uint2*)(crow1 + side * F + fc) = u1v;
            *(uint2*)(crow2 + side * F + fc) = u2v;
        }
    }
}

// ---- Out[:,off:off+N] = epi(A @ Bt^T); M-tile 32, N-tile 64; head-batched via blockIdx.z
__global__ __launch_bounds__(256) void k_ccgemm(const bf16* __restrict__ A0, const bf16* __restrict__ Bt0,
                                                bf16* __restrict__ Out, int K, int Ncols,
                                                int outStride, int outColOff0, int mode,
                                                long aHeadStride, long btHeadStride, int outColStep) {
    __shared__ __align__(16) bf16 Alds[32 * TNC];
    __shared__ __align__(16) bf16 Blds[64 * TNC];
    int h = blockIdx.z;
    const bf16* A = A0 + (size_t)h * aHeadStride;
    const bf16* Bt = Bt0 + (size_t)h * btHeadStride;
    int outColOff = outColOff0 + h * outColStep;
    int tid = threadIdx.x, lane = tid & 63, w = tid >> 6, wr = w >> 1, wc = w & 1;
    int m0 = blockIdx.y * 32, n0 = blockIdx.x * 64;
    int smA = tid >> 3, skA = (tid & 7) * 4;
    int smB = tid >> 2, skB = (tid & 3) * 8;
    f32x4 acc[2] = {};
    for (int k0 = 0; k0 < K; k0 += 32) {
        uint2 va = make_uint2(0, 0);
        uint4 vx = make_uint4(0, 0, 0, 0);
        if (k0 + skA < K) va = *(const uint2*)(A + (size_t)(m0 + smA) * K + k0 + skA);
        if (n0 + smB < Ncols && k0 + skB < K) vx = *(const uint4*)(Bt + (size_t)(n0 + smB) * K + k0 + skB);
        __syncthreads();
        *(uint2*)&Alds[smA * TNC + skA] = va;
        *(uint4*)&Blds[smB * TNC + skB] = vx;
        __syncthreads();
        int arr = wr * 16 + (lane & 15), koff = (lane >> 4) * 8;
        int br = wc * 32 + (lane & 15);
        short8v a0 = *(const short8v*)&Alds[arr * TNC + koff];
        short8v b0 = *(const short8v*)&Blds[br * TNC + koff];
        short8v b1 = *(const short8v*)&Blds[(br + 16) * TNC + koff];
        acc[0] = __builtin_amdgcn_mfma_f32_16x16x32_bf16(a0, b0, acc[0], 0, 0, 0);
        acc[1] = __builtin_amdgcn_mfma_f32_16x16x32_bf16(a0, b1, acc[1], 0, 0, 0);
    }
    for (int ni = 0; ni < 2; ni++) {
        int col = n0 + wc * 32 + ni * 16 + (lane & 15);
        if (col >= Ncols) continue;
        int rbase = m0 + wr * 16 + (lane >> 4) * 4;
        for (int r = 0; r < 4; r++) {
            float v = acc[ni][r];
            if (mode == 0) v = v > 0.f ? v : (__expf(v) - 1.0f);
            else           v = 1.0f / (1.0f + __expf(-v));
            Out[(size_t)(rbase + r) * outStride + outColOff + col] = __float2bfloat16(v);
        }
    }
}

__global__ void k_gather(const bf16* full, const int* ids, void* out, const int* flags) {
    int idx = blockIdx.x * 256 + threadIdx.x;
    if (idx >= 64 * DD) return;
    int t = idx / DD, d = idx - t * DD;
    float v = __bfloat162float(full[(size_t)ids[t] * DD + d]);
    if (flags[0]) ((float*)out)[idx] = v;
    else ((bf16*)out)[idx] = __float2bfloat16(v);
}

extern "C" void kernel_launch(void* const* d_in, const int* in_sizes, int n_in,
                              void* d_out, int out_size, void* d_ws, size_t ws_size,
                              hipStream_t stream) {
    const void* emb = d_in[0];
    const void* Whd = d_in[1];
    const void* ahd = d_in[2];
    const void* wth = d_in[3];
    const void* Wo  = d_in[4];
    const void* ao  = d_in[5];
    const void* wto = d_in[6];
    const void* adj = d_in[7];
    const int* tid  = (const int*)d_in[8];

    char* p = (char*)d_ws;
    auto alloc = [&](size_t bytes) { void* r = (void*)p; p += ((bytes + 255) / 256) * 256; return r; };
    int*     flags   = (int*)    alloc(256);
    uint8_t* adjbits = (uint8_t*)alloc((size_t)NND * NB8);
    bf16*  X1t   = (bf16*) alloc((size_t)320 * NND * 2);     // emb^T, padded to 320 rows
    bf16*  X2t   = (bf16*) alloc((size_t)1280 * NND * 2);    // x2^T, padded to 1280 rows
    bf16*  x2    = (bf16*) alloc((size_t)NND * F2 * 2);
    bf16*  cc4   = (bf16*) alloc((size_t)HH * NND * 2 * DD * 2);
    bf16*  ccO   = (bf16*) alloc((size_t)NND * 2 * F2 * 2);
    bf16*  wtT4  = (bf16*) alloc((size_t)HH * DD * 2 * DD * 2);
    bf16*  wtTo  = (bf16*) alloc((size_t)DD * 2 * F2 * 2);
    bf16*  ofull = (bf16*) alloc((size_t)NND * DD * 2);
    float* uh1   = (float*)alloc((size_t)HH * DD * 4);
    float* uh2   = (float*)alloc((size_t)HH * DD * 4);
    float* uo1   = (float*)alloc((size_t)F2 * 4);
    float* uo2   = (float*)alloc((size_t)F2 * 4);
    float* Wh1h  = (float*)alloc((size_t)HH * NND * 4);
    float* Wh2h  = (float*)alloc((size_t)HH * NND * 4);
    float* Wh1o  = (float*)alloc((size_t)NND * 4);
    float* Wh2o  = (float*)alloc((size_t)NND * 4);

    dim3 tb(32, 8);
    k_detect<<<1, 64, 0, stream>>>(emb, adj, flags);
    k_adjpack<<<NND, NB8, 0, stream>>>(adj, flags, adjbits);
    hipMemsetAsync(X1t, 0, (size_t)320 * NND * 2, stream);
    hipMemsetAsync(X2t, 0, (size_t)1280 * NND * 2, stream);
    // X1t = emb^T: [R=3072][C=300] -> grid (10, 96)
    k_transpose<<<dim3((DD + 31) / 32, (NND + 31) / 32), tb, 0, stream>>>(emb, 0, X1t, NND, DD, flags, 1);
    k_uvec<<<dim3((DD + 3) / 4, HH), 256, 0, stream>>>(Whd, ahd, uh1, uh2, DD, DD,
                                                       (long)DD * DD, (long)2 * DD, DD, flags);
    k_gemv2<<<dim3(NND / 4, HH), 256, 0, stream>>>(emb, uh1, uh2, Wh1h, Wh2h, NND, DD, DD, NND, flags, 1);
    // heads fused attention GEMM (operand-swapped, no LDS/barriers):
    // grid (i-groups=48, panels=4, heads=4) = 768 blocks x 128 threads = 1536 waves
    k_fatt2<<<dim3(48, 4, HH), 128, 0, stream>>>(Wh1h, Wh2h, NND, adjbits, X1t, cc4,
                                                 (long)NND * 2 * DD, 2 * DD, DD);
    // wth block is [R=600][C=300] -> grid (10, 19)
    for (int l = 0; l < HH; l++)
        k_transpose<<<dim3((DD + 31) / 32, (2 * DD + 31) / 32), tb, 0, stream>>>(
            wth, (size_t)l * 2 * DD * DD, wtT4 + (size_t)l * DD * 2 * DD, 2 * DD, DD, flags, 1);
    // head-batched concat GEMM with ELU -> x2 column blocks: grid (5, 96, 4)
    k_ccgemm<<<dim3(5, 96, HH), 256, 0, stream>>>(cc4, wtT4, x2, 2 * DD, DD, F2, 0, 0,
                                                  (long)NND * 2 * DD, (long)DD * 2 * DD, DD);
    // output layer
    k_transpose<<<dim3((F2 + 31) / 32, (NND + 31) / 32), tb, 0, stream>>>(x2, 0, X2t, NND, F2, flags, 0);
    k_uvec<<<dim3((F2 + 3) / 4, 1), 256, 0, stream>>>(Wo, ao, uo1, uo2, F2, DD, 0, 0, 0, flags);
    k_gemv2<<<dim3(NND / 4, 1), 256, 0, stream>>>(x2, uo1, uo2, Wh1o, Wh2o, NND, F2, 0, 0, flags, 0);
    // output fused attention GEMM: grid (48, 16, 1) = 768 blocks = 1536 waves
    k_fatt2<<<dim3(48, 16, 1), 128, 0, stream>>>(Wh1o, Wh2o, 0, adjbits, X2t, ccO,
                                                 0, 2 * F2, F2);
    // wto is [R=2400][C=300] -> grid (10, 75)
    k_transpose<<<dim3((DD + 31) / 32, (2 * F2 + 31) / 32), tb, 0, stream>>>(wto, 0, wtTo, 2 * F2, DD, flags, 1);
    k_ccgemm<<<dim3(5, 96, 1), 256, 0, stream>>>(ccO, wtTo, ofull, 2 * F2, DD, DD, 0, 1, 0, 0, 0);
    k_gather<<<(64 * DD + 255) / 256, 256, 0, stream>>>(ofull, tid, d_out, flags);
}

// Round 9
// 411.592 us; speedup vs baseline: 1.5239x; 1.1430x over previous
//
#include <hip/hip_runtime.h>
#include <hip/hip_bf16.h>
#include <stdint.h>

#define NND 3072
#define NB8 (NND / 8)      // adjbits row bytes = 384
#define DD 300
#define HH 4
#define F2 1200
#define TNC 40             // ccgemm LDS pad (32 + 8)
#define MREP 5             // fatt2 feature sub-tiles per wave (80 features)
#define PANEL (MREP * 16)
#define KHALF (NND / 2)

typedef __attribute__((ext_vector_type(8))) short short8v;
typedef __attribute__((ext_vector_type(4))) float f32x4;
typedef __hip_bfloat16 bf16;

__device__ inline float ldin(const void* p, size_t i, int isf32) {
    return isf32 ? ((const float*)p)[i]
                 : __bfloat162float(((const bf16*)p)[i]);
}

__device__ inline ushort f2bf(float x) {
    bf16 t = __float2bfloat16(x);
    return *reinterpret_cast<ushort*>(&t);
}

__device__ inline uint pack2(float lo, float hi) {
    return (uint)f2bf(lo) | ((uint)f2bf(hi) << 16);
}

// ---- dtype sniffer: flags[0]=1 iff float inputs are f32; flags[1]=1 iff adj is int32
__global__ void k_detect(const void* emb, const void* adj, int* flags) {
    if (threadIdx.x == 0 && blockIdx.x == 0) {
        const uint16_t* u = (const uint16_t*)emb;
        int plaus = 0;
        for (int i = 0; i < 128; i++) {
            int e = (u[i] >> 7) & 0xFF;
            if (e >= 112 && e <= 143) plaus++;
        }
        flags[0] = (plaus < 100) ? 1 : 0;
        const uint8_t* b = (const uint8_t*)adj;
        int nz = 0;
        for (int i = 0; i < 256; i++) if ((i & 3) != 0 && b[i]) nz++;
        flags[1] = (nz == 0) ? 1 : 0;
    }
}

// ---- pack adjacency to 1 bit per entry: adjbits[i][j/8]
__global__ void k_adjpack(const void* adj, const int* flags, uint8_t* bits) {
    int i = blockIdx.x, o = threadIdx.x;          // o = byte index 0..383 (8 j's each)
    int adjInt = flags[1];
    uint8_t b = 0;
    if (!adjInt) {
        const uint8_t* row = (const uint8_t*)adj + (size_t)i * NND + o * 8;
        uint2 v = *(const uint2*)row;
        #pragma unroll
        for (int jj = 0; jj < 4; jj++) {
            if ((v.x >> (8 * jj)) & 0xffu) b |= 1u << jj;
            if ((v.y >> (8 * jj)) & 0xffu) b |= 1u << (4 + jj);
        }
    } else {
        const int* row = (const int*)adj + (size_t)i * NND + o * 8;
        int4 u = *(const int4*)row;
        int4 v = *(const int4*)(row + 4);
        if (u.x) b |= 1;  if (u.y) b |= 2;   if (u.z) b |= 4;   if (u.w) b |= 8;
        if (v.x) b |= 16; if (v.y) b |= 32;  if (v.z) b |= 64;  if (v.w) b |= 128;
    }
    bits[(size_t)i * NB8 + o] = b;
}

// ---- T[c][r] = A[r][c], output bf16.  grid = ((C+31)/32, (R+31)/32)
__global__ void k_transpose(const void* A, size_t baseOff, bf16* T, int R, int C,
                            const int* flags, int useFlag) {
    __shared__ bf16 t[32][33];
    int isf = useFlag ? flags[0] : 0;
    int rt = blockIdx.y * 32, ct = blockIdx.x * 32;
    int tx = threadIdx.x, ty = threadIdx.y;
    for (int i = 0; i < 4; i++) {
        int r = rt + ty + 8 * i, c = ct + tx;
        if (r < R && c < C)
            t[ty + 8 * i][tx] = __float2bfloat16(ldin(A, baseOff + (size_t)r * C + c, isf));
    }
    __syncthreads();
    for (int i = 0; i < 4; i++) {
        int c = ct + ty + 8 * i, r = rt + tx;
        if (c < C && r < R) T[(size_t)c * R + r] = t[tx][ty + 8 * i];
    }
}

// ---- u1 = W @ a[:C], u2 = W @ a[C:2C]
__global__ void k_uvec(const void* W, const void* a, float* u1, float* u2, int R, int C,
                       long Wb, long ab, long ub, const int* flags) {
    int isf = flags[0];
    int h = blockIdx.y;
    int wid = threadIdx.x >> 6, lane = threadIdx.x & 63;
    int r = blockIdx.x * 4 + wid;
    if (r >= R) return;
    float s1 = 0.f, s2 = 0.f;
    for (int c = lane; c < C; c += 64) {
        float w = ldin(W, (size_t)h * Wb + (size_t)r * C + c, isf);
        s1 += w * ldin(a, (size_t)h * ab + c, isf);
        s2 += w * ldin(a, (size_t)h * ab + C + c, isf);
    }
    for (int o = 32; o; o >>= 1) { s1 += __shfl_down(s1, o); s2 += __shfl_down(s2, o); }
    if (lane == 0) { u1[(size_t)h * ub + r] = s1; u2[(size_t)h * ub + r] = s2; }
}

// ---- o1[i] = X[i,:]·u1, o2[i] = X[i,:]·u2
__global__ void k_gemv2(const void* X, const float* u1, const float* u2, float* o1, float* o2,
                        int M, int K, long ub, long ob, const int* flags, int useFlag) {
    int isf = useFlag ? flags[0] : 0;
    int h = blockIdx.y;
    const float* U1 = u1 + (size_t)h * ub;
    const float* U2 = u2 + (size_t)h * ub;
    int wid = threadIdx.x >> 6, lane = threadIdx.x & 63;
    int row = blockIdx.x * 4 + wid;
    if (row >= M) return;
    float s1 = 0.f, s2 = 0.f;
    for (int k = lane; k < K; k += 64) {
        float x = ldin(X, (size_t)row * K + k, isf);
        s1 += x * U1[k]; s2 += x * U2[k];
    }
    for (int o = 32; o; o >>= 1) { s1 += __shfl_down(s1, o); s2 += __shfl_down(s2, o); }
    if (lane == 0) { o1[(size_t)h * ob + row] = s1; o2[(size_t)h * ob + row] = s2; }
}

// ---- fused attention GEMM, operand-swapped + block-internal K-split.
// D[f][i] = sum_j Xt[f][j] * P^T[j][i]; P built in-register in the MFMA
// B-fragment layout. Wave w of the block owns K-half [w*1536, w*1536+1536):
// build work never duplicated across waves. One LDS merge + single barrier
// at block end (wave1 -> LDS, wave0 adds, scales by 1/rowsum, stores bf16).
__global__ __launch_bounds__(128, 3) void k_fatt2(
    const float* __restrict__ Wh1A, const float* __restrict__ Wh2A, long hs,
    const uint8_t* __restrict__ adjbits,
    const bf16* __restrict__ Xt,           // [rowsPad][NND] feature-major, zero-padded
    bf16* __restrict__ CC, long ccHeadStride, int ccStride, int F) {
    __shared__ float lmerge[64][85];       // 84 payload f32/lane, stride 85 (odd->bank spread)
    int h = blockIdx.z;
    const float* Wh1 = Wh1A + (size_t)h * hs;
    const float* Wh2 = Wh2A + (size_t)h * hs;
    bf16* C = CC + (size_t)h * ccHeadStride;
    int w = threadIdx.x >> 6, lane = threadIdx.x & 63;
    int fbase = blockIdx.y * PANEL;
    int ibase = blockIdx.x * 32;
    int i1 = ibase + (lane & 15), i2 = i1 + 16;
    int ksh = (lane >> 4) * 8;             // k-octet offset within 32-k step
    float w1a = Wh1[i1], w1b = Wh1[i2];
    const uint8_t* ab1 = adjbits + (size_t)i1 * NB8;
    const uint8_t* ab2 = adjbits + (size_t)i2 * NB8;
    const bf16* Abase = Xt + (size_t)(fbase + (lane & 15)) * NND + ksh;
    f32x4 acc[MREP][2][2] = {};            // [m][itile][side]
    float sp1 = 0.f, sn1 = 0.f, sp2 = 0.f, sn2 = 0.f;

    int kbeg = w * KHALF;
    for (int k0 = kbeg; k0 < kbeg + KHALF; k0 += 32) {
        uint m1 = *(const uint*)(ab1 + (k0 >> 3));
        uint m2 = *(const uint*)(ab2 + (k0 >> 3));
        float4 wa = *(const float4*)(Wh2 + k0 + ksh);
        float4 wb = *(const float4*)(Wh2 + k0 + ksh + 4);
        float zs0 = wa.x, zs1 = wa.y, zs2 = wa.z, zs3 = wa.w;
        float zs4 = wb.x, zs5 = wb.y, zs6 = wb.z, zs7 = wb.w;
        short8v bp1, bq1, bp2, bq2;
        #pragma unroll
        for (int jj = 0; jj < 8; jj++) {
            float zj = (jj == 0) ? zs0 : (jj == 1) ? zs1 : (jj == 2) ? zs2 : (jj == 3) ? zs3
                     : (jj == 4) ? zs4 : (jj == 5) ? zs5 : (jj == 6) ? zs6 : zs7;
            bool on1 = (m1 >> (ksh + jj)) & 1u;
            bool on2 = (m2 >> (ksh + jj)) & 1u;
            float z1 = w1a + zj;
            float e1 = fmaxf(z1, 0.3f * z1);
            float pe1 = on1 ? __expf(e1) : 0.0f;
            float qe1 = on1 ? __expf(-e1) : 0.0f;
            float z2 = w1b + zj;
            float e2 = fmaxf(z2, 0.3f * z2);
            float pe2 = on2 ? __expf(e2) : 0.0f;
            float qe2 = on2 ? __expf(-e2) : 0.0f;
            sp1 += pe1; sn1 += qe1; sp2 += pe2; sn2 += qe2;
            bp1[jj] = (short)f2bf(pe1); bq1[jj] = (short)f2bf(qe1);
            bp2[jj] = (short)f2bf(pe2); bq2[jj] = (short)f2bf(qe2);
        }
        #pragma unroll
        for (int m = 0; m < MREP; m++) {
            short8v a = *(const short8v*)(Abase + (size_t)m * 16 * NND + k0);
            acc[m][0][0] = __builtin_amdgcn_mfma_f32_16x16x32_bf16(a, bp1, acc[m][0][0], 0, 0, 0);
            acc[m][0][1] = __builtin_amdgcn_mfma_f32_16x16x32_bf16(a, bq1, acc[m][0][1], 0, 0, 0);
            acc[m][1][0] = __builtin_amdgcn_mfma_f32_16x16x32_bf16(a, bp2, acc[m][1][0], 0, 0, 0);
            acc[m][1][1] = __builtin_amdgcn_mfma_f32_16x16x32_bf16(a, bq2, acc[m][1][1], 0, 0, 0);
        }
    }

    // ---- K-half merge: wave1 deposits its partials; wave0 combines.
    if (w == 1) {
        #pragma unroll
        for (int m = 0; m < MREP; m++)
            #pragma unroll
            for (int it = 0; it < 2; it++)
                #pragma unroll
                for (int s = 0; s < 2; s++)
                    #pragma unroll
                    for (int r = 0; r < 4; r++)
                        lmerge[lane][((m * 2 + it) * 2 + s) * 4 + r] = acc[m][it][s][r];
        lmerge[lane][80] = sp1; lmerge[lane][81] = sn1;
        lmerge[lane][82] = sp2; lmerge[lane][83] = sn2;
    }
    __syncthreads();
    if (w == 1) return;
    #pragma unroll
    for (int m = 0; m < MREP; m++)
        #pragma unroll
        for (int it = 0; it < 2; it++)
            #pragma unroll
            for (int s = 0; s < 2; s++)
                #pragma unroll
                for (int r = 0; r < 4; r++)
                    acc[m][it][s][r] += lmerge[lane][((m * 2 + it) * 2 + s) * 4 + r];
    sp1 += lmerge[lane][80]; sn1 += lmerge[lane][81];
    sp2 += lmerge[lane][82]; sn2 += lmerge[lane][83];

    // full row sums: partials live on lanes sharing (lane&15); reduce over lane^16, lane^32
    sp1 += __shfl_xor(sp1, 16); sp1 += __shfl_xor(sp1, 32);
    sn1 += __shfl_xor(sn1, 16); sn1 += __shfl_xor(sn1, 32);
    sp2 += __shfl_xor(sp2, 16); sp2 += __shfl_xor(sp2, 32);
    sn2 += __shfl_xor(sn2, 16); sn2 += __shfl_xor(sn2, 32);
    float sc1[2] = { 1.0f / sp1, -1.0f / sn1 };
    float sc2[2] = { 1.0f / sp2, -1.0f / sn2 };
    int fo = (lane >> 4) * 4;
    bf16* crow1 = C + (size_t)i1 * ccStride;
    bf16* crow2 = C + (size_t)i2 * ccStride;
    #pragma unroll
    for (int m = 0; m < MREP; m++) {
        int fc = fbase + m * 16 + fo;
        if (fc >= F) continue;
        #pragma unroll
        for (int side = 0; side < 2; side++) {
            uint2 u1v, u2v;
            u1v.x = pack2(acc[m][0][side][0] * sc1[side], acc[m][0][side][1] * sc1[side]);
            u1v.y = pack2(acc[m][0][side][2] * sc1[side], acc[m][0][side][3] * sc1[side]);
            u2v.x = pack2(acc[m][1][side][0] * sc2[side], acc[m][1][side][1] * sc2[side]);
            u2v.y = pack2(acc[m][1][side][2] * sc2[side], acc[m][1][side][3] * sc2[side]);
            *(uint2*)(crow1 + side * F + fc) = u1v;
            *(uint2*)(crow2 + side * F + fc) = u2v;
        }
    }
}

// ---- Out[:,off:off+N] = epi(A @ Bt^T); M-tile 32, N-tile 64; head-batched via blockIdx.z
__global__ __launch_bounds__(256) void k_ccgemm(const bf16* __restrict__ A0, const bf16* __restrict__ Bt0,
                                                bf16* __restrict__ Out, int K, int Ncols,
                                                int outStride, int outColOff0, int mode,
                                                long aHeadStride, long btHeadStride, int outColStep) {
    __shared__ __align__(16) bf16 Alds[32 * TNC];
    __shared__ __align__(16) bf16 Blds[64 * TNC];
    int h = blockIdx.z;
    const bf16* A = A0 + (size_t)h * aHeadStride;
    const bf16* Bt = Bt0 + (size_t)h * btHeadStride;
    int outColOff = outColOff0 + h * outColStep;
    int tid = threadIdx.x, lane = tid & 63, w = tid >> 6, wr = w >> 1, wc = w & 1;
    int m0 = blockIdx.y * 32, n0 = blockIdx.x * 64;
    int smA = tid >> 3, skA = (tid & 7) * 4;
    int smB = tid >> 2, skB = (tid & 3) * 8;
    f32x4 acc[2] = {};
    for (int k0 = 0; k0 < K; k0 += 32) {
        uint2 va = make_uint2(0, 0);
        uint4 vx = make_uint4(0, 0, 0, 0);
        if (k0 + skA < K) va = *(const uint2*)(A + (size_t)(m0 + smA) * K + k0 + skA);
        if (n0 + smB < Ncols && k0 + skB < K) vx = *(const uint4*)(Bt + (size_t)(n0 + smB) * K + k0 + skB);
        __syncthreads();
        *(uint2*)&Alds[smA * TNC + skA] = va;
        *(uint4*)&Blds[smB * TNC + skB] = vx;
        __syncthreads();
        int arr = wr * 16 + (lane & 15), koff = (lane >> 4) * 8;
        int br = wc * 32 + (lane & 15);
        short8v a0 = *(const short8v*)&Alds[arr * TNC + koff];
        short8v b0 = *(const short8v*)&Blds[br * TNC + koff];
        short8v b1 = *(const short8v*)&Blds[(br + 16) * TNC + koff];
        acc[0] = __builtin_amdgcn_mfma_f32_16x16x32_bf16(a0, b0, acc[0], 0, 0, 0);
        acc[1] = __builtin_amdgcn_mfma_f32_16x16x32_bf16(a0, b1, acc[1], 0, 0, 0);
    }
    for (int ni = 0; ni < 2; ni++) {
        int col = n0 + wc * 32 + ni * 16 + (lane & 15);
        if (col >= Ncols) continue;
        int rbase = m0 + wr * 16 + (lane >> 4) * 4;
        for (int r = 0; r < 4; r++) {
            float v = acc[ni][r];
            if (mode == 0) v = v > 0.f ? v : (__expf(v) - 1.0f);
            else           v = 1.0f / (1.0f + __expf(-v));
            Out[(size_t)(rbase + r) * outStride + outColOff + col] = __float2bfloat16(v);
        }
    }
}

__global__ void k_gather(const bf16* full, const int* ids, void* out, const int* flags) {
    int idx = blockIdx.x * 256 + threadIdx.x;
    if (idx >= 64 * DD) return;
    int t = idx / DD, d = idx - t * DD;
    float v = __bfloat162float(full[(size_t)ids[t] * DD + d]);
    if (flags[0]) ((float*)out)[idx] = v;
    else ((bf16*)out)[idx] = __float2bfloat16(v);
}

extern "C" void kernel_launch(void* const* d_in, const int* in_sizes, int n_in,
                              void* d_out, int out_size, void* d_ws, size_t ws_size,
                              hipStream_t stream) {
    const void* emb = d_in[0];
    const void* Whd = d_in[1];
    const void* ahd = d_in[2];
    const void* wth = d_in[3];
    const void* Wo  = d_in[4];
    const void* ao  = d_in[5];
    const void* wto = d_in[6];
    const void* adj = d_in[7];
    const int* tid  = (const int*)d_in[8];

    char* p = (char*)d_ws;
    auto alloc = [&](size_t bytes) { void* r = (void*)p; p += ((bytes + 255) / 256) * 256; return r; };
    int*     flags   = (int*)    alloc(256);
    uint8_t* adjbits = (uint8_t*)alloc((size_t)NND * NB8);
    bf16*  X1t   = (bf16*) alloc((size_t)320 * NND * 2);     // emb^T, padded to 320 rows
    bf16*  X2t   = (bf16*) alloc((size_t)1280 * NND * 2);    // x2^T, padded to 1280 rows
    bf16*  x2    = (bf16*) alloc((size_t)NND * F2 * 2);
    bf16*  cc4   = (bf16*) alloc((size_t)HH * NND * 2 * DD * 2);
    bf16*  ccO   = (bf16*) alloc((size_t)NND * 2 * F2 * 2);
    bf16*  wtT4  = (bf16*) alloc((size_t)HH * DD * 2 * DD * 2);
    bf16*  wtTo  = (bf16*) alloc((size_t)DD * 2 * F2 * 2);
    bf16*  ofull = (bf16*) alloc((size_t)NND * DD * 2);
    float* uh1   = (float*)alloc((size_t)HH * DD * 4);
    float* uh2   = (float*)alloc((size_t)HH * DD * 4);
    float* uo1   = (float*)alloc((size_t)F2 * 4);
    float* uo2   = (float*)alloc((size_t)F2 * 4);
    float* Wh1h  = (float*)alloc((size_t)HH * NND * 4);
    float* Wh2h  = (float*)alloc((size_t)HH * NND * 4);
    float* Wh1o  = (float*)alloc((size_t)NND * 4);
    float* Wh2o  = (float*)alloc((size_t)NND * 4);

    dim3 tb(32, 8);
    k_detect<<<1, 64, 0, stream>>>(emb, adj, flags);
    k_adjpack<<<NND, NB8, 0, stream>>>(adj, flags, adjbits);
    hipMemsetAsync(X1t, 0, (size_t)320 * NND * 2, stream);
    hipMemsetAsync(X2t, 0, (size_t)1280 * NND * 2, stream);
    // X1t = emb^T: [R=3072][C=300] -> grid (10, 96)
    k_transpose<<<dim3((DD + 31) / 32, (NND + 31) / 32), tb, 0, stream>>>(emb, 0, X1t, NND, DD, flags, 1);
    k_uvec<<<dim3((DD + 3) / 4, HH), 256, 0, stream>>>(Whd, ahd, uh1, uh2, DD, DD,
                                                       (long)DD * DD, (long)2 * DD, DD, flags);
    k_gemv2<<<dim3(NND / 4, HH), 256, 0, stream>>>(emb, uh1, uh2, Wh1h, Wh2h, NND, DD, DD, NND, flags, 1);
    // heads fused attention GEMM (K-split x2 in-block):
    // grid (i-blocks=96, panels=4, heads=4) = 1536 blocks x 2 waves = 3072 waves
    k_fatt2<<<dim3(96, 4, HH), 128, 0, stream>>>(Wh1h, Wh2h, NND, adjbits, X1t, cc4,
                                                 (long)NND * 2 * DD, 2 * DD, DD);
    // wth block is [R=600][C=300] -> grid (10, 19)
    for (int l = 0; l < HH; l++)
        k_transpose<<<dim3((DD + 31) / 32, (2 * DD + 31) / 32), tb, 0, stream>>>(
            wth, (size_t)l * 2 * DD * DD, wtT4 + (size_t)l * DD * 2 * DD, 2 * DD, DD, flags, 1);
    // head-batched concat GEMM with ELU -> x2 column blocks: grid (5, 96, 4)
    k_ccgemm<<<dim3(5, 96, HH), 256, 0, stream>>>(cc4, wtT4, x2, 2 * DD, DD, F2, 0, 0,
                                                  (long)NND * 2 * DD, (long)DD * 2 * DD, DD);
    // output layer
    k_transpose<<<dim3((F2 + 31) / 32, (NND + 31) / 32), tb, 0, stream>>>(x2, 0, X2t, NND, F2, flags, 0);
    k_uvec<<<dim3((F2 + 3) / 4, 1), 256, 0, stream>>>(Wo, ao, uo1, uo2, F2, DD, 0, 0, 0, flags);
    k_gemv2<<<dim3(NND / 4, 1), 256, 0, stream>>>(x2, uo1, uo2, Wh1o, Wh2o, NND, F2, 0, 0, flags, 0);
    // output fused attention GEMM: grid (96, 15, 1) = 1440 blocks = 2880 waves
    k_fatt2<<<dim3(96, 15, 1), 128, 0, stream>>>(Wh1o, Wh2o, 0, adjbits, X2t, ccO,
                                                 0, 2 * F2, F2);
    // wto is [R=2400][C=300] -> grid (10, 75)
    k_transpose<<<dim3((DD + 31) / 32, (2 * F2 + 31) / 32), tb, 0, stream>>>(wto, 0, wtTo, 2 * F2, DD, flags, 1);
    k_ccgemm<<<dim3(5, 96, 1), 256, 0, stream>>>(ccO, wtTo, ofull, 2 * F2, DD, DD, 0, 1, 0, 0, 0);
    k_gather<<<(64 * DD + 255) / 256, 256, 0, stream>>>(ofull, tid, d_out, flags);
}